// Round 3
// baseline (3157.242 us; speedup 1.0000x reference)
//
#include <hip/hip_runtime.h>

#define T_SEQ 2048
#define NBATCH 64
#define DIM 128      // SEQ_LEN
#define HID 128      // HIDDEN
#define G4 512       // 4*HID

typedef _Float16 h2v __attribute__((ext_vector_type(2)));

__device__ __forceinline__ unsigned pack2(float lo, float hi) {
    h2v v; v.x = (_Float16)lo; v.y = (_Float16)hi;
    return __builtin_bit_cast(unsigned, v);
}
__device__ __forceinline__ float dot2(unsigned a, unsigned b, float c) {
#if __has_builtin(__builtin_amdgcn_fdot2)
    return __builtin_amdgcn_fdot2(__builtin_bit_cast(h2v, a),
                                  __builtin_bit_cast(h2v, b), c, false);
#else
    h2v av = __builtin_bit_cast(h2v, a), bv = __builtin_bit_cast(h2v, b);
    c = fmaf((float)av.x, (float)bv.x, c);
    return fmaf((float)av.y, (float)bv.y, c);
#endif
}
__device__ __forceinline__ unsigned bcast(unsigned v, int l) {
    return (unsigned)__builtin_amdgcn_readlane((int)v, l);
}
__device__ __forceinline__ float sigmoidf_(float x) {
    return 1.0f / (1.0f + __expf(-x));
}
__device__ __forceinline__ float tanhf_(float x) {
    float e = __expf(-2.0f * fabsf(x));
    float t = __fdividef(1.0f - e, 1.0f + e);
    return copysignf(t, x);
}

// ---- Phase 1: pre16[lt][b][unit j][gate q] = f16( x[b][t] . W_ih[:, q*128+j] + bias )
// grid.x = tc, block = 128 threads (one per hidden unit, 4 gate cols each)
__global__ __launch_bounds__(128, 1) void pre_gemm16(
    const float* __restrict__ x,      // [B][T][DIM]
    const float* __restrict__ Wih,    // [DIM][G4]
    const float* __restrict__ bias,   // [G4]
    _Float16* __restrict__ pre,       // [tc][B][HID][4]
    int t0)
{
    __shared__ unsigned xs[NBATCH][64];   // packed f16 pairs of x rows
    const int lt = blockIdx.x;
    const int t  = t0 + lt;
    const int j  = threadIdx.x;           // unit
    const int lane = j & 63;

    for (int i = j; i < NBATCH * 64; i += 128) {
        int row  = i >> 6;
        int word = i & 63;
        float2 v = *reinterpret_cast<const float2*>(
            x + (size_t)row * (T_SEQ * DIM) + (size_t)t * DIM + word * 2);
        xs[row][word] = pack2(v.x, v.y);
    }

    unsigned wI[64], wF[64], wG[64], wO[64];
    #pragma unroll
    for (int k = 0; k < 64; ++k) {
        const float* r0 = Wih + (size_t)(2 * k) * G4;
        const float* r1 = Wih + (size_t)(2 * k + 1) * G4;
        wI[k] = pack2(r0[j],       r1[j]);
        wF[k] = pack2(r0[j + 128], r1[j + 128]);
        wG[k] = pack2(r0[j + 256], r1[j + 256]);
        wO[k] = pack2(r0[j + 384], r1[j + 384]);
    }
    __syncthreads();
    const float bI = bias[j], bF = bias[j + 128], bG = bias[j + 256], bO = bias[j + 384];

    for (int b = 0; b < NBATCH; ++b) {
        unsigned xw = xs[b][lane];        // lane l holds packed pair (x[2l], x[2l+1])
        float ai = bI, af = bF, ag = bG, ao = bO;
        #pragma unroll
        for (int k = 0; k < 64; ++k) {
            unsigned hk = bcast(xw, k);
            ai = dot2(hk, wI[k], ai);
            af = dot2(hk, wF[k], af);
            ag = dot2(hk, wG[k], ag);
            ao = dot2(hk, wO[k], ao);
        }
        h2v p01; p01.x = (_Float16)ai; p01.y = (_Float16)af;
        h2v p23; p23.x = (_Float16)ag; p23.y = (_Float16)ao;
        uint2 w; w.x = __builtin_bit_cast(unsigned, p01);
                 w.y = __builtin_bit_cast(unsigned, p23);
        *reinterpret_cast<uint2*>(pre + ((size_t)lt * NBATCH + b) * G4 + 4 * j) = w;
    }
}

// ---- Phase 2: sequential scan. grid.x = batch (64), block = 128 threads (one per unit).
// state layout (floats): h[64*128] | c[64*128] | facc0[64*128] | facc1[64*128]
__global__ __launch_bounds__(128, 1) void lstm_scan(
    const _Float16* __restrict__ pre, // [tc][B][HID][4]
    const float* __restrict__ Whh,    // [HID][G4]
    const float* __restrict__ h0,
    const float* __restrict__ c0,
    const float* __restrict__ fcw,    // [2][T*HID]
    const float* __restrict__ fcb,    // [2]
    float* __restrict__ state,
    float* __restrict__ out,          // [B][2]
    int t0, int tc)
{
    __shared__ _Float16 h_sh[2][HID];     // double-buffered h (packed-pair readable)
    __shared__ float red[2][HID];

    const int b = blockIdx.x;
    const int j = threadIdx.x;            // unit
    const int lane = j & 63;

    float* st_h  = state;
    float* st_c  = state + NBATCH * HID;
    float* st_f0 = state + 2 * NBATCH * HID;
    float* st_f1 = state + 3 * NBATCH * HID;

    unsigned wI[64], wF[64], wG[64], wO[64];
    #pragma unroll
    for (int k = 0; k < 64; ++k) {
        const float* r0 = Whh + (size_t)(2 * k) * G4;
        const float* r1 = Whh + (size_t)(2 * k + 1) * G4;
        wI[k] = pack2(r0[j],       r1[j]);
        wF[k] = pack2(r0[j + 128], r1[j + 128]);
        wG[k] = pack2(r0[j + 256], r1[j + 256]);
        wO[k] = pack2(r0[j + 384], r1[j + 384]);
    }

    float c, facc0, facc1, hj;
    if (t0 == 0) {
        hj = h0[b * HID + j]; c = c0[b * HID + j]; facc0 = 0.f; facc1 = 0.f;
    } else {
        hj    = st_h[b * HID + j];
        c     = st_c[b * HID + j];
        facc0 = st_f0[b * HID + j];
        facc1 = st_f1[b * HID + j];
    }
    h_sh[0][j] = (_Float16)hj;
    __syncthreads();

    const size_t pstep = (size_t)NBATCH * G4;         // halves per timestep
    const _Float16* pb = pre + (size_t)b * G4 + 4 * j;

    for (int g8 = 0; g8 < tc; g8 += 4) {
        const int gs = (tc - g8 < 4) ? (tc - g8) : 4;
        uint2 pq[4];
        float f0q[4], f1q[4];
        #pragma unroll
        for (int s = 0; s < 4; ++s) {
            if (s < gs) {
                pq[s] = *reinterpret_cast<const uint2*>(pb + (size_t)(g8 + s) * pstep);
                int t = t0 + g8 + s;
                f0q[s] = fcw[(size_t)t * HID + j];
                f1q[s] = fcw[(size_t)T_SEQ * HID + (size_t)t * HID + j];
            }
        }
        #pragma unroll
        for (int s = 0; s < 4; ++s) {
            if (s < gs) {
                const int cur = (g8 + s) & 1;
                unsigned hword = *reinterpret_cast<const unsigned*>(&h_sh[cur][2 * lane]);
                h2v plo = __builtin_bit_cast(h2v, pq[s].x);
                h2v phi = __builtin_bit_cast(h2v, pq[s].y);
                float ai = (float)plo.x, af = (float)plo.y;
                float ag = (float)phi.x, ao = (float)phi.y;
                #pragma unroll
                for (int k = 0; k < 64; ++k) {
                    unsigned hk = bcast(hword, k);
                    ai = dot2(hk, wI[k], ai);
                    af = dot2(hk, wF[k], af);
                    ag = dot2(hk, wG[k], ag);
                    ao = dot2(hk, wO[k], ao);
                }
                float gi = sigmoidf_(ai);
                float gf = sigmoidf_(af);
                float gg = tanhf_(ag);
                float go = sigmoidf_(ao);
                c = fmaf(gf, c, gi * gg);
                float hn = go * tanhf_(c);
                facc0 = fmaf(hn, f0q[s], facc0);
                facc1 = fmaf(hn, f1q[s], facc1);
                h_sh[cur ^ 1][j] = (_Float16)hn;      // write other buffer: no read race
                hj = hn;
                __syncthreads();                       // one barrier per step
            }
        }
    }

    if (t0 + tc >= T_SEQ) {
        red[0][j] = facc0; red[1][j] = facc1;
        __syncthreads();
        if (j == 0) {
            float s0 = 0.f, s1 = 0.f;
            for (int k = 0; k < HID; ++k) { s0 += red[0][k]; s1 += red[1][k]; }
            out[b * 2 + 0] = s0 + fcb[0];
            out[b * 2 + 1] = s1 + fcb[1];
        }
    } else {
        st_h[b * HID + j]  = hj;
        st_c[b * HID + j]  = c;
        st_f0[b * HID + j] = facc0;
        st_f1[b * HID + j] = facc1;
    }
}

extern "C" void kernel_launch(void* const* d_in, const int* in_sizes, int n_in,
                              void* d_out, int out_size, void* d_ws, size_t ws_size,
                              hipStream_t stream) {
    const float* x    = (const float*)d_in[0];
    const float* h0   = (const float*)d_in[1];
    const float* c0   = (const float*)d_in[2];
    const float* Wih  = (const float*)d_in[3];
    const float* Whh  = (const float*)d_in[4];
    const float* bias = (const float*)d_in[5];
    const float* fcw  = (const float*)d_in[6];
    const float* fcb  = (const float*)d_in[7];
    float* out = (float*)d_out;

    // ws layout: state header (4 * 64*128 floats = 128 KB), then f16 pre chunk buffer
    float* state = (float*)d_ws;
    const size_t state_floats = (size_t)4 * NBATCH * HID;
    _Float16* pre = (_Float16*)(state + state_floats);

    const size_t per_t_bytes = (size_t)NBATCH * G4 * sizeof(_Float16); // 64 KB per timestep
    size_t avail = (ws_size > state_floats * sizeof(float))
                       ? ws_size - state_floats * sizeof(float) : 0;
    int Tc = (int)(avail / per_t_bytes);
    Tc &= ~7;                       // keep group-of-4 alignment comfortable
    if (Tc < 8) Tc = 8;             // degenerate fallback (assumes ws >= ~640 KB)
    if (Tc > T_SEQ) Tc = T_SEQ;

    for (int t0 = 0; t0 < T_SEQ; t0 += Tc) {
        int tc = (t0 + Tc <= T_SEQ) ? Tc : (T_SEQ - t0);
        pre_gemm16<<<tc, 128, 0, stream>>>(x, Wih, bias, pre, t0);
        lstm_scan<<<64, 128, 0, stream>>>(pre, Whh, h0, c0, fcw, fcb,
                                          state, out, t0, tc);
    }
}

// Round 4
// 1929.433 us; speedup vs baseline: 1.6364x; 1.6364x over previous
//
#include <hip/hip_runtime.h>

#define T_SEQ 2048
#define NBATCH 64
#define DIM 128      // SEQ_LEN
#define HID 128      // HIDDEN
#define G4 512       // 4*HID
#define GRP 8        // steps per load-batch group

typedef _Float16 h2v __attribute__((ext_vector_type(2)));

__device__ __forceinline__ unsigned pack2(float lo, float hi) {
    h2v v; v.x = (_Float16)lo; v.y = (_Float16)hi;
    return __builtin_bit_cast(unsigned, v);
}
__device__ __forceinline__ float dot2(unsigned a, unsigned b, float c) {
#if __has_builtin(__builtin_amdgcn_fdot2)
    return __builtin_amdgcn_fdot2(__builtin_bit_cast(h2v, a),
                                  __builtin_bit_cast(h2v, b), c, false);
#else
    h2v av = __builtin_bit_cast(h2v, a), bv = __builtin_bit_cast(h2v, b);
    c = fmaf((float)av.x, (float)bv.x, c);
    return fmaf((float)av.y, (float)bv.y, c);
#endif
}
__device__ __forceinline__ unsigned bcast(unsigned v, int l) {
    return (unsigned)__builtin_amdgcn_readlane((int)v, l);
}
__device__ __forceinline__ float sigmoidf_(float x) {
    return 1.0f / (1.0f + __expf(-x));
}
__device__ __forceinline__ float tanhf_(float x) {
    float e = __expf(-2.0f * fabsf(x));
    float t = __fdividef(1.0f - e, 1.0f + e);
    return copysignf(t, x);
}

// ---------------- Phase 1: pre16[lt][b][g] = f16( x[b][t][:] @ W_ih[:,g] + bias[g] ) -----
// grid.x = tc (local timestep), block = 512 threads (one per gate column g)
__global__ __launch_bounds__(512, 2) void pre_gemm16(
    const float* __restrict__ x,      // [B][T][DIM]
    const float* __restrict__ Wih,    // [DIM][G4]
    const float* __restrict__ bias,   // [G4]
    _Float16* __restrict__ pre,       // [tc][B][G4]
    int t0)
{
    __shared__ unsigned xs[NBATCH][64];   // packed f16 pairs of x rows
    const int lt = blockIdx.x;
    const int t  = t0 + lt;
    const int g  = threadIdx.x;
    const int lane = g & 63;

    for (int i = g; i < NBATCH * 64; i += 512) {
        int row  = i >> 6;
        int word = i & 63;
        float2 v = *reinterpret_cast<const float2*>(
            x + (size_t)row * (T_SEQ * DIM) + (size_t)t * DIM + word * 2);
        xs[row][word] = pack2(v.x, v.y);
    }

    unsigned wpk[64];
    #pragma unroll
    for (int i = 0; i < 64; ++i)
        wpk[i] = pack2(Wih[(size_t)(2 * i) * G4 + g],
                       Wih[(size_t)(2 * i + 1) * G4 + g]);

    __syncthreads();
    const float bg = bias[g];

    for (int b = 0; b < NBATCH; ++b) {
        unsigned xw = xs[b][lane];         // lane l holds packed pair (x[2l], x[2l+1])
        float a0 = bg, a1 = 0.f, a2 = 0.f, a3 = 0.f;
        #pragma unroll
        for (int k = 0; k < 64; k += 4) {
            a0 = dot2(bcast(xw, k + 0), wpk[k + 0], a0);
            a1 = dot2(bcast(xw, k + 1), wpk[k + 1], a1);
            a2 = dot2(bcast(xw, k + 2), wpk[k + 2], a2);
            a3 = dot2(bcast(xw, k + 3), wpk[k + 3], a3);
        }
        pre[((size_t)lt * NBATCH + b) * G4 + g] = (_Float16)((a0 + a1) + (a2 + a3));
    }
}

// ---------------- Phase 2: sequential LSTM scan ----------------
// grid.x = batch b (64 blocks), block = 512 threads (one per gate column g)
// state layout (floats): h[64*128] | c[64*128] | facc0[64*128] | facc1[64*128]
__global__ __launch_bounds__(512, 2) void lstm_scan(
    const _Float16* __restrict__ pre, // [tc][B][G4]
    const float* __restrict__ Whh,    // [HID][G4]
    const float* __restrict__ h0,
    const float* __restrict__ c0,
    const float* __restrict__ fcw,    // [2][T*HID]
    const float* __restrict__ fcb,    // [2]
    float* __restrict__ state,
    float* __restrict__ out,          // [B][2]
    int t0, int tc)
{
    __shared__ _Float16 h_buf[2][HID];    // double-buffered h
    __shared__ float gate_sh[G4];
    __shared__ float red[2][HID];

    const int b = blockIdx.x;
    const int g = threadIdx.x;
    const int lane = g & 63;
    const int gtype = g >> 7;             // 0:i 1:f 2:g 3:o (wave-uniform)

    float* st_h  = state;
    float* st_c  = state + NBATCH * HID;
    float* st_f0 = state + 2 * NBATCH * HID;
    float* st_f1 = state + 3 * NBATCH * HID;

    // W_hh column g, packed f16 pairs, in registers (64 VGPRs)
    unsigned wpk[64];
    #pragma unroll
    for (int k = 0; k < 64; ++k)
        wpk[k] = pack2(Whh[(size_t)(2 * k) * G4 + g],
                       Whh[(size_t)(2 * k + 1) * G4 + g]);

    float c = 0.f, facc0 = 0.f, facc1 = 0.f, hj = 0.f;
    if (g < HID) {
        if (t0 == 0) {
            hj = h0[b * HID + g]; c = c0[b * HID + g];
        } else {
            hj    = st_h[b * HID + g];
            c     = st_c[b * HID + g];
            facc0 = st_f0[b * HID + g];
            facc1 = st_f1[b * HID + g];
        }
        h_buf[0][g] = (_Float16)hj;
    }
    __syncthreads();

    const size_t pstep = (size_t)NBATCH * G4;          // halves per timestep
    const _Float16* pb = pre + (size_t)b * G4 + g;

    for (int tg = 0; tg < tc; tg += GRP) {
        // ---- batched global loads for GRP steps (issued right after a barrier;
        //      their latency is covered by the first step's dot work) ----
        unsigned short pr[GRP];
        float f0[GRP], f1[GRP];
        #pragma unroll
        for (int s = 0; s < GRP; ++s)
            pr[s] = *reinterpret_cast<const unsigned short*>(
                        pb + (size_t)(tg + s) * pstep);
        if (g < HID) {
            #pragma unroll
            for (int s = 0; s < GRP; ++s) {
                size_t t = (size_t)(t0 + tg + s);
                f0[s] = fcw[t * HID + g];
                f1[s] = fcw[(size_t)T_SEQ * HID + t * HID + g];
            }
        }

        #pragma unroll
        for (int s = 0; s < GRP; ++s) {
            const int cur = s & 1;        // tg is a multiple of GRP (even)
            unsigned hword = *reinterpret_cast<const unsigned*>(&h_buf[cur][2 * lane]);
            float a0 = (float)__builtin_bit_cast(_Float16, pr[s]);
            float a1 = 0.f, a2 = 0.f, a3 = 0.f;
            #pragma unroll
            for (int k = 0; k < 64; k += 4) {
                a0 = dot2(bcast(hword, k + 0), wpk[k + 0], a0);
                a1 = dot2(bcast(hword, k + 1), wpk[k + 1], a1);
                a2 = dot2(bcast(hword, k + 2), wpk[k + 2], a2);
                a3 = dot2(bcast(hword, k + 3), wpk[k + 3], a3);
            }
            float acc = (a0 + a1) + (a2 + a3);
            float act = (gtype == 2) ? tanhf_(acc) : sigmoidf_(acc);
            gate_sh[g] = act;
            __syncthreads();

            if (g < HID) {
                float gi = gate_sh[g];
                float gf = gate_sh[g + 128];
                float gg = gate_sh[g + 256];
                float go = gate_sh[g + 384];
                c = fmaf(gf, c, gi * gg);
                float hn = go * tanhf_(c);
                hj = hn;
                h_buf[cur ^ 1][g] = (_Float16)hn;
                facc0 = fmaf(hn, f0[s], facc0);
                facc1 = fmaf(hn, f1[s], facc1);
            }
            __syncthreads();
        }
    }

    if (t0 + tc >= T_SEQ) {
        if (g < HID) { red[0][g] = facc0; red[1][g] = facc1; }
        __syncthreads();
        if (g == 0) {
            float s0 = 0.f, s1 = 0.f;
            for (int k = 0; k < HID; ++k) { s0 += red[0][k]; s1 += red[1][k]; }
            out[b * 2 + 0] = s0 + fcb[0];
            out[b * 2 + 1] = s1 + fcb[1];
        }
    } else {
        if (g < HID) {
            st_h[b * HID + g]  = hj;
            st_c[b * HID + g]  = c;
            st_f0[b * HID + g] = facc0;
            st_f1[b * HID + g] = facc1;
        }
    }
}

extern "C" void kernel_launch(void* const* d_in, const int* in_sizes, int n_in,
                              void* d_out, int out_size, void* d_ws, size_t ws_size,
                              hipStream_t stream) {
    const float* x    = (const float*)d_in[0];
    const float* h0   = (const float*)d_in[1];
    const float* c0   = (const float*)d_in[2];
    const float* Wih  = (const float*)d_in[3];
    const float* Whh  = (const float*)d_in[4];
    const float* bias = (const float*)d_in[5];
    const float* fcw  = (const float*)d_in[6];
    const float* fcb  = (const float*)d_in[7];
    float* out = (float*)d_out;

    // ws layout: state header (4 * 64*128 floats = 128 KB), then f16 pre chunk buffer
    float* state = (float*)d_ws;
    const size_t state_floats = (size_t)4 * NBATCH * HID;
    _Float16* pre = (_Float16*)(state + state_floats);

    const size_t per_t_bytes = (size_t)NBATCH * G4 * sizeof(_Float16); // 64 KB per timestep
    size_t avail = (ws_size > state_floats * sizeof(float))
                       ? ws_size - state_floats * sizeof(float) : 0;
    int Tc = (int)(avail / per_t_bytes);
    Tc &= ~(GRP - 1);               // multiple of GRP so the scan needs no tail guards
    if (Tc < GRP) Tc = GRP;         // fallback (assumes ws >= ~640 KB)
    if (Tc > T_SEQ) Tc = T_SEQ;

    for (int t0 = 0; t0 < T_SEQ; t0 += Tc) {
        int tc = (t0 + Tc <= T_SEQ) ? Tc : (T_SEQ - t0);   // stays multiple of GRP
        pre_gemm16<<<tc, 512, 0, stream>>>(x, Wih, bias, pre, t0);
        lstm_scan<<<64, 512, 0, stream>>>(pre, Whh, h0, c0, fcw, fcb,
                                          state, out, t0, tc);
    }
}

// Round 5
// 1431.028 us; speedup vs baseline: 2.2063x; 1.3483x over previous
//
#include <hip/hip_runtime.h>

#define T_SEQ 2048
#define NBATCH 64
#define DIM 128      // SEQ_LEN
#define HID 128      // HIDDEN
#define G4 512       // 4*HID
#define GRP 16       // steps per load-batch group

typedef _Float16 h2v __attribute__((ext_vector_type(2)));

__device__ __forceinline__ unsigned pack2(float lo, float hi) {
    h2v v; v.x = (_Float16)lo; v.y = (_Float16)hi;
    return __builtin_bit_cast(unsigned, v);
}
__device__ __forceinline__ float dot2(unsigned a, unsigned b, float c) {
#if __has_builtin(__builtin_amdgcn_fdot2)
    return __builtin_amdgcn_fdot2(__builtin_bit_cast(h2v, a),
                                  __builtin_bit_cast(h2v, b), c, false);
#else
    h2v av = __builtin_bit_cast(h2v, a), bv = __builtin_bit_cast(h2v, b);
    c = fmaf((float)av.x, (float)bv.x, c);
    return fmaf((float)av.y, (float)bv.y, c);
#endif
}
__device__ __forceinline__ unsigned bcast(unsigned v, int l) {
    return (unsigned)__builtin_amdgcn_readlane((int)v, l);
}
__device__ __forceinline__ float rcp_(float x) {
    return __builtin_amdgcn_rcpf(x);
}
__device__ __forceinline__ float sigmoidf_(float x) {
    return rcp_(1.0f + __expf(-x));
}
__device__ __forceinline__ float tanhf_(float x) {
    // 2/(1+exp(-2x)) - 1 ; exp->inf and exp->0 limits are exact
    return fmaf(2.0f, rcp_(1.0f + __expf(-2.0f * x)), -1.0f);
}
// quad-butterfly add via DPP quad_perm (stays on VALU pipe)
template <int CTRL>
__device__ __forceinline__ float qadd(float v) {
    int r = __builtin_amdgcn_mov_dpp(__builtin_bit_cast(int, v), CTRL, 0xF, 0xF, true);
    return v + __builtin_bit_cast(float, r);
}
__device__ __forceinline__ float quad_reduce(float v) {
    v = qadd<0xB1>(v);   // xor 1: quad_perm [1,0,3,2]
    v = qadd<0x4E>(v);   // xor 2: quad_perm [2,3,0,1]
    return v;
}

// ---- Phase 1: pre16[lt][b][unit*4+gate] = f16( x[b][t] . W_ih[:,gate*128+unit] + bias )
// grid.x = tc, block = 512. Thread g computes column (g&3)*128 + (g>>2); writes offset g.
__global__ __launch_bounds__(512, 2) void pre_gemm16(
    const float* __restrict__ x,      // [B][T][DIM]
    const float* __restrict__ Wih,    // [DIM][G4]
    const float* __restrict__ bias,   // [G4]
    _Float16* __restrict__ pre,       // [tc][B][G4] in unit-major interleave
    int t0)
{
    __shared__ unsigned xs[NBATCH][64];   // packed f16 pairs of x rows
    const int lt = blockIdx.x;
    const int t  = t0 + lt;
    const int g  = threadIdx.x;
    const int lane = g & 63;
    const int col = (g & 3) * HID + (g >> 2);   // gate*128 + unit

    for (int i = g; i < NBATCH * 64; i += 512) {
        int row  = i >> 6;
        int word = i & 63;
        float2 v = *reinterpret_cast<const float2*>(
            x + (size_t)row * (T_SEQ * DIM) + (size_t)t * DIM + word * 2);
        xs[row][word] = pack2(v.x, v.y);
    }

    unsigned wpk[64];
    #pragma unroll
    for (int i = 0; i < 64; ++i)
        wpk[i] = pack2(Wih[(size_t)(2 * i) * G4 + col],
                       Wih[(size_t)(2 * i + 1) * G4 + col]);

    __syncthreads();
    const float bg = bias[col];

    for (int b = 0; b < NBATCH; ++b) {
        unsigned xw = xs[b][lane];
        float a0 = bg, a1 = 0.f, a2 = 0.f, a3 = 0.f;
        #pragma unroll
        for (int k = 0; k < 64; k += 4) {
            a0 = dot2(bcast(xw, k + 0), wpk[k + 0], a0);
            a1 = dot2(bcast(xw, k + 1), wpk[k + 1], a1);
            a2 = dot2(bcast(xw, k + 2), wpk[k + 2], a2);
            a3 = dot2(bcast(xw, k + 3), wpk[k + 3], a3);
        }
        pre[((size_t)lt * NBATCH + b) * G4 + g] = (_Float16)((a0 + a1) + (a2 + a3));
    }
}

// ---- Phase 2: scan. grid.x = batch (64 blocks), block = 512: thread = unit j (tid>>2),
//      k-quarter q (tid&3). One barrier + one broadcast LDS read per step.
// state layout (floats): h[64*128] | c[64*128] | facc0[64*128] | facc1[64*128]
__global__ __launch_bounds__(512, 1) void lstm_scan(
    const _Float16* __restrict__ pre, // [tc][B][G4] unit-major interleave
    const float* __restrict__ Whh,    // [HID][G4]
    const float* __restrict__ h0,
    const float* __restrict__ c0,
    const float* __restrict__ fcw,    // [2][T*HID]
    const float* __restrict__ fcb,    // [2]
    float* __restrict__ state,
    float* __restrict__ out,          // [B][2]
    int t0, int tc)
{
    __shared__ __align__(16) _Float16 h_sh[2][HID];  // double-buffered h
    __shared__ float red[2][HID];

    const int tid = threadIdx.x;
    const int j = tid >> 2;           // unit
    const int q = tid & 3;            // k-quarter
    const int b = blockIdx.x;

    float* st_h  = state;
    float* st_c  = state + NBATCH * HID;
    float* st_f0 = state + 2 * NBATCH * HID;
    float* st_f1 = state + 3 * NBATCH * HID;

    // W_hh fragments: gate g, k in [32q, 32q+32), packed pairs (64 VGPRs)
    unsigned wpk[4][16];
    #pragma unroll
    for (int g = 0; g < 4; ++g)
        #pragma unroll
        for (int i = 0; i < 16; ++i) {
            int k0 = q * 32 + 2 * i;
            wpk[g][i] = pack2(Whh[(size_t)k0 * G4 + g * HID + j],
                              Whh[(size_t)(k0 + 1) * G4 + g * HID + j]);
        }

    float c, facc = 0.f, hj;
    if (t0 == 0) {
        hj = h0[b * HID + j]; c = c0[b * HID + j];
    } else {
        hj = st_h[b * HID + j];
        c  = st_c[b * HID + j];
        if (q == 2) facc = st_f0[b * HID + j];
        if (q == 3) facc = st_f1[b * HID + j];
    }
    if (q == 0) h_sh[0][j] = (_Float16)hj;

    const float* fp = fcw + ((q == 3) ? (size_t)T_SEQ * HID : 0) + j;  // used when q>=2
    const size_t pstep = (size_t)NBATCH * G4;
    const _Float16* pb = pre + (size_t)b * G4 + tid;

    __syncthreads();

    for (int tg = 0; tg < tc; tg += GRP) {
        // batched global loads for GRP steps (drained at first barrier below;
        // ~one L3 latency exposed per GRP steps)
        unsigned short pr[GRP];
        float fw[GRP];
        #pragma unroll
        for (int s = 0; s < GRP; ++s)
            pr[s] = __builtin_bit_cast(unsigned short, pb[(size_t)(tg + s) * pstep]);
        if (q >= 2) {
            #pragma unroll
            for (int s = 0; s < GRP; ++s)
                fw[s] = fp[(size_t)(t0 + tg + s) * HID];
        }

        #pragma unroll
        for (int s = 0; s < GRP; ++s) {
            const int cur = s & 1;    // tg is a multiple of GRP (even)
            const uint4* hp = reinterpret_cast<const uint4*>(&h_sh[cur][q * 32]);
            float pv = (float)__builtin_bit_cast(_Float16, pr[s]);
            float a0 = (q == 0) ? pv : 0.f;
            float a1 = (q == 1) ? pv : 0.f;
            float a2 = (q == 2) ? pv : 0.f;
            float a3 = (q == 3) ? pv : 0.f;
            #pragma unroll
            for (int m = 0; m < 4; ++m) {
                uint4 hv = hp[m];
                a0 = dot2(hv.x, wpk[0][4 * m + 0], a0);
                a1 = dot2(hv.x, wpk[1][4 * m + 0], a1);
                a2 = dot2(hv.x, wpk[2][4 * m + 0], a2);
                a3 = dot2(hv.x, wpk[3][4 * m + 0], a3);
                a0 = dot2(hv.y, wpk[0][4 * m + 1], a0);
                a1 = dot2(hv.y, wpk[1][4 * m + 1], a1);
                a2 = dot2(hv.y, wpk[2][4 * m + 1], a2);
                a3 = dot2(hv.y, wpk[3][4 * m + 1], a3);
                a0 = dot2(hv.z, wpk[0][4 * m + 2], a0);
                a1 = dot2(hv.z, wpk[1][4 * m + 2], a1);
                a2 = dot2(hv.z, wpk[2][4 * m + 2], a2);
                a3 = dot2(hv.z, wpk[3][4 * m + 2], a3);
                a0 = dot2(hv.w, wpk[0][4 * m + 3], a0);
                a1 = dot2(hv.w, wpk[1][4 * m + 3], a1);
                a2 = dot2(hv.w, wpk[2][4 * m + 3], a2);
                a3 = dot2(hv.w, wpk[3][4 * m + 3], a3);
            }
            // quad butterfly: all 4 lanes get all 4 gate totals
            a0 = quad_reduce(a0);
            a1 = quad_reduce(a1);
            a2 = quad_reduce(a2);
            a3 = quad_reduce(a3);

            float gi = sigmoidf_(a0);
            float gf = sigmoidf_(a1);
            float gg = tanhf_(a2);
            float go = sigmoidf_(a3);
            c = fmaf(gf, c, gi * gg);
            float hn = go * tanhf_(c);
            hj = hn;
            if (q == 0) h_sh[cur ^ 1][j] = (_Float16)hn;
            if (q >= 2) facc = fmaf(hn, fw[s], facc);
            __syncthreads();
        }
    }

    if (t0 + tc >= T_SEQ) {
        if (q == 2) red[0][j] = facc;
        if (q == 3) red[1][j] = facc;
        __syncthreads();
        if (tid < 128) {
            int o = tid >> 6;         // 0 or 1 (wave 0 -> out0, wave 1 -> out1)
            int l = tid & 63;
            float v = red[o][l] + red[o][l + 64];
            v += __shfl_xor(v, 32); v += __shfl_xor(v, 16);
            v += __shfl_xor(v, 8);  v += __shfl_xor(v, 4);
            v += __shfl_xor(v, 2);  v += __shfl_xor(v, 1);
            if (l == 0) out[b * 2 + o] = v + fcb[o];
        }
    } else {
        if (q == 0) { st_h[b * HID + j] = hj; st_c[b * HID + j] = c; }
        if (q == 2) st_f0[b * HID + j] = facc;
        if (q == 3) st_f1[b * HID + j] = facc;
    }
}

extern "C" void kernel_launch(void* const* d_in, const int* in_sizes, int n_in,
                              void* d_out, int out_size, void* d_ws, size_t ws_size,
                              hipStream_t stream) {
    const float* x    = (const float*)d_in[0];
    const float* h0   = (const float*)d_in[1];
    const float* c0   = (const float*)d_in[2];
    const float* Wih  = (const float*)d_in[3];
    const float* Whh  = (const float*)d_in[4];
    const float* bias = (const float*)d_in[5];
    const float* fcw  = (const float*)d_in[6];
    const float* fcb  = (const float*)d_in[7];
    float* out = (float*)d_out;

    // ws layout: state header (4 * 64*128 floats = 128 KB), then f16 pre chunk buffer
    float* state = (float*)d_ws;
    const size_t state_floats = (size_t)4 * NBATCH * HID;
    _Float16* pre = (_Float16*)(state + state_floats);

    const size_t per_t_bytes = (size_t)NBATCH * G4 * sizeof(_Float16); // 64 KB per timestep
    size_t avail = (ws_size > state_floats * sizeof(float))
                       ? ws_size - state_floats * sizeof(float) : 0;
    int Tc = (int)(avail / per_t_bytes);
    Tc &= ~(GRP - 1);               // multiple of GRP so the scan needs no tail guards
    if (Tc < GRP) Tc = GRP;         // fallback (assumes ws >= ~1.2 MB)
    if (Tc > T_SEQ) Tc = T_SEQ;

    for (int t0 = 0; t0 < T_SEQ; t0 += Tc) {
        int tc = (t0 + Tc <= T_SEQ) ? Tc : (T_SEQ - t0);   // stays multiple of GRP
        pre_gemm16<<<tc, 512, 0, stream>>>(x, Wih, bias, pre, t0);
        lstm_scan<<<64, 512, 0, stream>>>(pre, Whh, h0, c0, fcw, fcb,
                                          state, out, t0, tc);
    }
}

// Round 6
// 1394.821 us; speedup vs baseline: 2.2635x; 1.0260x over previous
//
#include <hip/hip_runtime.h>

#define T_SEQ 2048
#define NBATCH 64
#define DIM 128      // SEQ_LEN
#define HID 128      // HIDDEN
#define G4 512       // 4*HID
#define GRP 16       // steps per load-batch group

typedef _Float16 h2v __attribute__((ext_vector_type(2)));

__device__ __forceinline__ unsigned pack2(float lo, float hi) {
    h2v v; v.x = (_Float16)lo; v.y = (_Float16)hi;
    return __builtin_bit_cast(unsigned, v);
}
__device__ __forceinline__ float dot2(unsigned a, unsigned b, float c) {
#if __has_builtin(__builtin_amdgcn_fdot2)
    return __builtin_amdgcn_fdot2(__builtin_bit_cast(h2v, a),
                                  __builtin_bit_cast(h2v, b), c, false);
#else
    h2v av = __builtin_bit_cast(h2v, a), bv = __builtin_bit_cast(h2v, b);
    c = fmaf((float)av.x, (float)bv.x, c);
    return fmaf((float)av.y, (float)bv.y, c);
#endif
}
__device__ __forceinline__ unsigned bcast(unsigned v, int l) {
    return (unsigned)__builtin_amdgcn_readlane((int)v, l);
}
__device__ __forceinline__ float rcp_(float x) {
    return __builtin_amdgcn_rcpf(x);
}
__device__ __forceinline__ float sigmoidf_(float x) {
    return rcp_(1.0f + __expf(-x));
}
__device__ __forceinline__ float tanhf_(float x) {
    return fmaf(2.0f, rcp_(1.0f + __expf(-2.0f * x)), -1.0f);
}
// DPP helpers (quad_perm)
template <int CTRL>
__device__ __forceinline__ float qmov(float v) {
    int r = __builtin_amdgcn_mov_dpp(__builtin_bit_cast(int, v), CTRL, 0xF, 0xF, true);
    return __builtin_bit_cast(float, r);
}
#define QP_XOR1 0xB1   // [1,0,3,2]
#define QP_XOR2 0x4E   // [2,3,0,1]
#define QP_B0   0x00   // [0,0,0,0]
#define QP_B1   0x55   // [1,1,1,1]
#define QP_B2   0xAA   // [2,2,2,2]
#define QP_B3   0xFF   // [3,3,3,3]

// barrier that drains ONLY lgkm (ds) — vm loads keep flowing across it
__device__ __forceinline__ void barrier_lgkm() {
    asm volatile("s_waitcnt lgkmcnt(0)\n\ts_barrier" ::: "memory");
    __builtin_amdgcn_sched_barrier(0);
}

// ---- Phase 1: pre16[lt][b][unit*4+gate] = f16( x[b][t] . W_ih[:,gate*128+unit] + bias )
// grid.x = tc, block = 512. Thread g computes column (g&3)*128 + (g>>2); writes offset g.
__global__ __launch_bounds__(512, 2) void pre_gemm16(
    const float* __restrict__ x,      // [B][T][DIM]
    const float* __restrict__ Wih,    // [DIM][G4]
    const float* __restrict__ bias,   // [G4]
    _Float16* __restrict__ pre,       // [tc][B][G4] unit-major interleave
    int t0)
{
    __shared__ unsigned xs[NBATCH][64];
    const int lt = blockIdx.x;
    const int t  = t0 + lt;
    const int g  = threadIdx.x;
    const int lane = g & 63;
    const int col = (g & 3) * HID + (g >> 2);

    for (int i = g; i < NBATCH * 64; i += 512) {
        int row  = i >> 6;
        int word = i & 63;
        float2 v = *reinterpret_cast<const float2*>(
            x + (size_t)row * (T_SEQ * DIM) + (size_t)t * DIM + word * 2);
        xs[row][word] = pack2(v.x, v.y);
    }

    unsigned wpk[64];
    #pragma unroll
    for (int i = 0; i < 64; ++i)
        wpk[i] = pack2(Wih[(size_t)(2 * i) * G4 + col],
                       Wih[(size_t)(2 * i + 1) * G4 + col]);

    __syncthreads();
    const float bg = bias[col];

    for (int b = 0; b < NBATCH; ++b) {
        unsigned xw = xs[b][lane];
        float a0 = bg, a1 = 0.f, a2 = 0.f, a3 = 0.f;
        #pragma unroll
        for (int k = 0; k < 64; k += 4) {
            a0 = dot2(bcast(xw, k + 0), wpk[k + 0], a0);
            a1 = dot2(bcast(xw, k + 1), wpk[k + 1], a1);
            a2 = dot2(bcast(xw, k + 2), wpk[k + 2], a2);
            a3 = dot2(bcast(xw, k + 3), wpk[k + 3], a3);
        }
        pre[((size_t)lt * NBATCH + b) * G4 + g] = (_Float16)((a0 + a1) + (a2 + a3));
    }
}

// ---- Phase 2: scan. grid.x = batch (64 blocks), block = 512: thread = (unit j = tid>>2,
//      k-quarter q = tid&3). Reduce-scatter + per-lane gate activation + DPP gather.
// state layout (floats): h[64*128] | c[64*128] | facc0[64*128] | facc1[64*128]
__global__ __launch_bounds__(512, 1) void lstm_scan(
    const _Float16* __restrict__ pre, // [tc][B][G4] unit-major interleave
    const float* __restrict__ Whh,    // [HID][G4]
    const float* __restrict__ h0,
    const float* __restrict__ c0,
    const float* __restrict__ fcw,    // [2][T*HID]
    const float* __restrict__ fcb,    // [2]
    float* __restrict__ state,
    float* __restrict__ out,          // [B][2]
    int t0, int tc)
{
    __shared__ __align__(16) _Float16 h_sh[2][HID];
    __shared__ float red[2][HID];

    const int tid = threadIdx.x;
    const int j = tid >> 2;           // unit
    const int q = tid & 3;            // k-quarter / gate owner
    const int b = blockIdx.x;
    const bool q1 = (q & 1) != 0;
    const bool q2 = (q & 2) != 0;
    const bool isg = (q == 2);        // gate 'g' uses tanh

    float* st_h  = state;
    float* st_c  = state + NBATCH * HID;
    float* st_f0 = state + 2 * NBATCH * HID;
    float* st_f1 = state + 3 * NBATCH * HID;

    // W_hh fragments: gate g, k in [32q, 32q+32), packed pairs (64 VGPRs)
    unsigned wpk[4][16];
    #pragma unroll
    for (int g = 0; g < 4; ++g)
        #pragma unroll
        for (int i = 0; i < 16; ++i) {
            int k0 = q * 32 + 2 * i;
            wpk[g][i] = pack2(Whh[(size_t)k0 * G4 + g * HID + j],
                              Whh[(size_t)(k0 + 1) * G4 + g * HID + j]);
        }

    float c, facc = 0.f, hj;
    if (t0 == 0) {
        hj = h0[b * HID + j]; c = c0[b * HID + j];
    } else {
        hj = st_h[b * HID + j];
        c  = st_c[b * HID + j];
        if (q == 2) facc = st_f0[b * HID + j];
        if (q == 3) facc = st_f1[b * HID + j];
    }
    if (q == 0) h_sh[0][j] = (_Float16)hj;

    const float* fp = fcw + ((q == 3) ? (size_t)T_SEQ * HID : 0) + j;  // q>=2 only
    const size_t pstep = (size_t)NBATCH * G4;
    const _Float16* pb = pre + (size_t)b * G4 + tid;

    __syncthreads();

    for (int tg = 0; tg < tc; tg += GRP) {
        // batched global loads for GRP steps — drain lazily (no vmcnt(0) at barriers)
        unsigned short pr[GRP];
        float fw[GRP];
        #pragma unroll
        for (int s = 0; s < GRP; ++s)
            pr[s] = __builtin_bit_cast(unsigned short, pb[(size_t)(tg + s) * pstep]);
        if (q >= 2) {
            #pragma unroll
            for (int s = 0; s < GRP; ++s)
                fw[s] = fp[(size_t)(t0 + tg + s) * HID];
        }

        #pragma unroll
        for (int s = 0; s < GRP; ++s) {
            const int cur = s & 1;    // tg is a multiple of GRP (even)
            const uint4* hp = reinterpret_cast<const uint4*>(&h_sh[cur][q * 32]);
            float pv = (float)__builtin_bit_cast(_Float16, pr[s]);
            float a0 = (q == 0) ? pv : 0.f;
            float a1 = (q == 1) ? pv : 0.f;
            float a2 = (q == 2) ? pv : 0.f;
            float a3 = (q == 3) ? pv : 0.f;
            #pragma unroll
            for (int m = 0; m < 4; ++m) {
                uint4 hv = hp[m];
                a0 = dot2(hv.x, wpk[0][4 * m + 0], a0);
                a1 = dot2(hv.x, wpk[1][4 * m + 0], a1);
                a2 = dot2(hv.x, wpk[2][4 * m + 0], a2);
                a3 = dot2(hv.x, wpk[3][4 * m + 0], a3);
                a0 = dot2(hv.y, wpk[0][4 * m + 1], a0);
                a1 = dot2(hv.y, wpk[1][4 * m + 1], a1);
                a2 = dot2(hv.y, wpk[2][4 * m + 1], a2);
                a3 = dot2(hv.y, wpk[3][4 * m + 1], a3);
                a0 = dot2(hv.z, wpk[0][4 * m + 2], a0);
                a1 = dot2(hv.z, wpk[1][4 * m + 2], a1);
                a2 = dot2(hv.z, wpk[2][4 * m + 2], a2);
                a3 = dot2(hv.z, wpk[3][4 * m + 2], a3);
                a0 = dot2(hv.w, wpk[0][4 * m + 3], a0);
                a1 = dot2(hv.w, wpk[1][4 * m + 3], a1);
                a2 = dot2(hv.w, wpk[2][4 * m + 3], a2);
                a3 = dot2(hv.w, wpk[3][4 * m + 3], a3);
            }
            // reduce-scatter: lane q ends with the FULL sum of gate q
            float t01  = q1 ? a1 : a0;
            float t01o = q1 ? a0 : a1;
            t01 += qmov<QP_XOR1>(t01o);
            float t23  = q1 ? a3 : a2;
            float t23o = q1 ? a2 : a3;
            t23 += qmov<QP_XOR1>(t23o);
            float tq  = q2 ? t23 : t01;
            float tqo = q2 ? t01 : t23;
            tq += qmov<QP_XOR2>(tqo);

            // specialized activation: 1 exp + 1 rcp per lane
            float e   = __expf(isg ? -2.0f * tq : -tq);
            float v   = rcp_(1.0f + e);
            float act = isg ? fmaf(2.0f, v, -1.0f) : v;

            // gather gates by quad broadcast
            float gi = qmov<QP_B0>(act);
            float gf = qmov<QP_B1>(act);
            float gg = qmov<QP_B2>(act);
            float go = qmov<QP_B3>(act);

            c = fmaf(gf, c, gi * gg);
            float hn = go * tanhf_(c);
            hj = hn;
            if (q == 0) h_sh[cur ^ 1][j] = (_Float16)hn;
            if (q >= 2) facc = fmaf(hn, fw[s], facc);
            barrier_lgkm();
        }
    }

    if (t0 + tc >= T_SEQ) {
        if (q == 2) red[0][j] = facc;
        if (q == 3) red[1][j] = facc;
        __syncthreads();
        if (tid < 128) {
            int o = tid >> 6;
            int l = tid & 63;
            float v = red[o][l] + red[o][l + 64];
            v += __shfl_xor(v, 32); v += __shfl_xor(v, 16);
            v += __shfl_xor(v, 8);  v += __shfl_xor(v, 4);
            v += __shfl_xor(v, 2);  v += __shfl_xor(v, 1);
            if (l == 0) out[b * 2 + o] = v + fcb[o];
        }
    } else {
        if (q == 0) { st_h[b * HID + j] = hj; st_c[b * HID + j] = c; }
        if (q == 2) st_f0[b * HID + j] = facc;
        if (q == 3) st_f1[b * HID + j] = facc;
    }
}

extern "C" void kernel_launch(void* const* d_in, const int* in_sizes, int n_in,
                              void* d_out, int out_size, void* d_ws, size_t ws_size,
                              hipStream_t stream) {
    const float* x    = (const float*)d_in[0];
    const float* h0   = (const float*)d_in[1];
    const float* c0   = (const float*)d_in[2];
    const float* Wih  = (const float*)d_in[3];
    const float* Whh  = (const float*)d_in[4];
    const float* bias = (const float*)d_in[5];
    const float* fcw  = (const float*)d_in[6];
    const float* fcb  = (const float*)d_in[7];
    float* out = (float*)d_out;

    float* state = (float*)d_ws;
    const size_t state_floats = (size_t)4 * NBATCH * HID;
    _Float16* pre = (_Float16*)(state + state_floats);

    const size_t per_t_bytes = (size_t)NBATCH * G4 * sizeof(_Float16); // 64 KB per timestep
    size_t avail = (ws_size > state_floats * sizeof(float))
                       ? ws_size - state_floats * sizeof(float) : 0;
    int Tc = (int)(avail / per_t_bytes);
    Tc &= ~(GRP - 1);
    if (Tc < GRP) Tc = GRP;
    if (Tc > T_SEQ) Tc = T_SEQ;

    for (int t0 = 0; t0 < T_SEQ; t0 += Tc) {
        int tc = (t0 + Tc <= T_SEQ) ? Tc : (T_SEQ - t0);
        pre_gemm16<<<tc, 512, 0, stream>>>(x, Wih, bias, pre, t0);
        lstm_scan<<<64, 512, 0, stream>>>(pre, Whh, h0, c0, fcw, fcb,
                                          state, out, t0, tc);
    }
}